// Round 1
// 2254.418 us; speedup vs baseline: 1.0196x; 1.0196x over previous
//
#include <hip/hip_runtime.h>
#include <cstdint>

typedef __attribute__((ext_vector_type(8))) short bf16x8;
typedef __attribute__((ext_vector_type(4))) float f32x4;
typedef unsigned short u16;
typedef unsigned int u32;
typedef unsigned long long u64;

#define T_STEPS 256
#define BATCH 64
#define HID 256
#define VOCAB 5000
#define KC 768            // 3*HID
#define NWG 16
#define HB 16             // HID / NWG
#define NPAD 5120         // 40*128

// ---------- helpers ----------
__device__ __forceinline__ u16 f2bf(float x) {
  union { float f; u32 u; } v; v.f = x;
  u32 r = v.u + 0x7fffu + ((v.u >> 16) & 1u);
  return (u16)(r >> 16);
}
__device__ __forceinline__ float bf2f(u16 b) {
  union { float f; u32 u; } v; v.u = ((u32)b) << 16;
  return v.f;
}
__device__ __forceinline__ void load_lds16(const void* g, void* l) {
  __builtin_amdgcn_global_load_lds(
      (const __attribute__((address_space(1))) void*)g,
      (__attribute__((address_space(3))) void*)l, 16, 0, 0);
}
// Device-coherent 2B store: write-through L1/L2 to the coherent point (L3).
// No output regs -> no inline-asm load hazards; ordering vs the flag store is
// enforced by the explicit s_waitcnt vmcnt(0) below.
__device__ __forceinline__ void st_u16_coh(u16* p, u16 v) {
  asm volatile("global_store_short %0, %1, off sc0 sc1" :: "v"(p), "v"((u32)v));
}
// Device-coherent 8B load (compiler-tracked vmcnt; pipelines across calls).
__device__ __forceinline__ u64 ld_u64_coh(const u16* p) {
  return __hip_atomic_load((const u64*)p, __ATOMIC_RELAXED, __HIP_MEMORY_SCOPE_AGENT);
}
// fast sigmoid / tanh via v_exp_f32 + v_rcp_f32 (err ~1e-6, << bf16 rounding)
__device__ __forceinline__ float fsig(float x) {
  return __builtin_amdgcn_rcpf(1.f + __expf(-x));
}
__device__ __forceinline__ float ftanh(float x) {
  return 1.f - 2.f * __builtin_amdgcn_rcpf(1.f + __expf(2.f * x));
}

// ---------- prep: B' transposed [NPAD][KC] bf16, rows: [W_hi; W_hi; W_lo] ----------
__global__ __launch_bounds__(256) void prep_b(const float* __restrict__ Wd,
                                              u16* __restrict__ BT) {
  int gid = blockIdx.x * 256 + threadIdx.x;   // [0, 5120*96)
  int n = gid / 96;
  int k0 = (gid % 96) * 8;
  union { uint4 q; u16 s[8]; } o;
#pragma unroll
  for (int i = 0; i < 8; ++i) {
    int k = k0 + i;
    float x = 0.f;
    if (n < VOCAB) {
      int kk = (k < 512) ? (k & 255) : (k - 512);
      x = Wd[kk * VOCAB + n];
    }
    u16 hi = f2bf(x);
    o.s[i] = (k < 512) ? hi : f2bf(x - bf2f(hi));
  }
  *(uint4*)(BT + (size_t)n * KC + k0) = o.q;
}

// ---------- prep: h0 split hi/lo into A'-row-shaped scratch ----------
__global__ __launch_bounds__(256) void prep_h0(const float* __restrict__ h0,
                                               u16* __restrict__ H0S) {
  int i = blockIdx.x * 256 + threadIdx.x;  // 16384
  int b = i >> 8, j = i & 255;
  float x = h0[i];
  u16 hi = f2bf(x);
  u16 lo = f2bf(x - bf2f(hi));
  H0S[b * KC + j] = hi;
  H0S[b * KC + 256 + j] = lo;
}

// ---------- recurrence: 16 WGs, hidden-split, register-resident weights ----------
// Exchange protocol (this round's change): h hi/lo segments are written with
// sc0|sc1 write-through stores and read with sc0|sc1 (agent-relaxed-atomic)
// loads, so NO threadfence (buffer_wbl2 / buffer_inv) is needed per step.
// L2 stays warm across steps (embedding table gathers become L2 hits).
// One flag per WAVE (64 flags): each wave publishes after its own vmcnt(0);
// no __syncthreads in the step loop at all (waves share nothing intra-WG).
__global__ __launch_bounds__(256, 1) void gru_rec(
    const int* __restrict__ tokens, const float* __restrict__ h0,
    const float* __restrict__ ker, const float* __restrict__ rker,
    const float* __restrict__ bias,
    u16* __restrict__ Abuf, const u16* __restrict__ H0S,
    float* __restrict__ hlast, u32* __restrict__ flags) {
  const int g = blockIdx.x;
  const int tid = threadIdx.x;
  const int w = tid >> 6;        // wave id = m-tile
  const int l = tid & 63;
  const int lm = l & 15;
  const int lq = l >> 4;

  int cmap[3]; float brec[3], bin[3];
#pragma unroll
  for (int nt = 0; nt < 3; ++nt) {
    cmap[nt] = nt * 256 + g * HB + lm;
    bin[nt]  = bias[cmap[nt]];
    brec[nt] = bias[KC + cmap[nt]];
  }

  // Step-invariant B-fragments: rk_slice hi/lo, B[k][n]: n=lane&15, k=quad*8+j
  bf16x8 Bhi[3][8], Blo[3][8];
#pragma unroll
  for (int nt = 0; nt < 3; ++nt)
#pragma unroll
    for (int kb = 0; kb < 8; ++kb) {
      union { bf16x8 v; u16 s[8]; } uh, ul;
#pragma unroll
      for (int jj = 0; jj < 8; ++jj) {
        int k = kb * 32 + lq * 8 + jj;
        float x = rker[k * KC + cmap[nt]];
        u16 hi = f2bf(x);
        uh.s[jj] = hi;
        ul.s[jj] = f2bf(x - bf2f(hi));
      }
      Bhi[nt][kb] = uh.v; Blo[nt][kb] = ul.v;
    }

  // own h in f32, D-layout: row b = 16w + lq*4 + r, col j = g*HB + lm
  float hown[4];
#pragma unroll
  for (int r = 0; r < 4; ++r)
    hown[r] = h0[(16 * w + lq * 4 + r) * HID + g * HB + lm];

  const int rowloc = 16 * w + lm;   // A-frag row (m = lane&15)

  // token prefetch one step ahead (breaks token->gather serial chain)
  int ntok[4];
#pragma unroll
  for (int r = 0; r < 4; ++r)
    ntok[r] = tokens[(16 * w + lq * 4 + r) * T_STEPS];

  for (int t = 0; t < T_STEPS; ++t) {
    int ctok[4];
#pragma unroll
    for (int r = 0; r < 4; ++r) ctok[r] = ntok[r];
    if (t + 1 < T_STEPS) {
#pragma unroll
      for (int r = 0; r < 4; ++r)
        ntok[r] = tokens[(16 * w + lq * 4 + r) * T_STEPS + t + 1];
    }

    // embedding gathers — independent of flags, issued before the spin;
    // L2-resident now that we no longer invalidate L2 every step
    float mx[3][4];
#pragma unroll
    for (int r = 0; r < 4; ++r) {
#pragma unroll
      for (int nt = 0; nt < 3; ++nt)
        mx[nt][r] = ker[(size_t)ctok[r] * KC + cmap[nt]] + bin[nt];
    }

    if (t > 0) {
      const u32 tt = (u32)t;
      int guard = 0;
      for (;;) {
        // 64 per-wave flags, one per lane; relaxed agent load = sc0 sc1 (L3)
        u32 v = __hip_atomic_load(&flags[l * 32], __ATOMIC_RELAXED,
                                  __HIP_MEMORY_SCOPE_AGENT);
        if (__all((int)(v >= tt))) break;
        if (++guard > (1 << 24)) break;   // safety valve (never expected)
        __builtin_amdgcn_s_sleep(1);
      }
      // no acquire fence needed: data loads below are sc0|sc1 (bypass L1/L2),
      // and the producer's write-through stores reached L3 before its flag.
    }

    const u16* hsrc = (t == 0) ? H0S : (Abuf + (size_t)(t - 1) * BATCH * KC);
    const u16* hrow = hsrc + (size_t)rowloc * KC;
    bf16x8 Ahi[8], Alo[8];
#pragma unroll
    for (int kb = 0; kb < 8; ++kb) {
      union { u64 d[2]; bf16x8 v; } a0, a1;
      const u16* p0 = hrow + kb * 32 + lq * 8;
      const u16* p1 = hrow + 256 + kb * 32 + lq * 8;
      a0.d[0] = ld_u64_coh(p0);
      a0.d[1] = ld_u64_coh(p0 + 4);
      a1.d[0] = ld_u64_coh(p1);
      a1.d[1] = ld_u64_coh(p1 + 4);
      Ahi[kb] = a0.v; Alo[kb] = a1.v;
    }

    f32x4 acc[3];
#pragma unroll
    for (int nt = 0; nt < 3; ++nt)
      acc[nt] = (f32x4){brec[nt], brec[nt], brec[nt], brec[nt]};

#pragma unroll
    for (int kb = 0; kb < 8; ++kb) {
#pragma unroll
      for (int nt = 0; nt < 3; ++nt) {
        acc[nt] = __builtin_amdgcn_mfma_f32_16x16x32_bf16(Ahi[kb], Bhi[nt][kb], acc[nt], 0, 0, 0);
        acc[nt] = __builtin_amdgcn_mfma_f32_16x16x32_bf16(Alo[kb], Bhi[nt][kb], acc[nt], 0, 0, 0);
        acc[nt] = __builtin_amdgcn_mfma_f32_16x16x32_bf16(Ahi[kb], Blo[nt][kb], acc[nt], 0, 0, 0);
      }
    }

#pragma unroll
    for (int r = 0; r < 4; ++r) {
      float z  = fsig(acc[0][r] + mx[0][r]);
      float rr = fsig(acc[1][r] + mx[1][r]);
      float cd = ftanh(mx[2][r] + rr * acc[2][r]);   // reset_after candidate
      float hn = z * hown[r] + (1.f - z) * cd;
      hown[r] = hn;
      u16 hi = f2bf(hn);
      u16 lo = f2bf(hn - bf2f(hi));
      int b = 16 * w + lq * 4 + r;
      u16* orow = Abuf + (size_t)(t * BATCH + b) * KC;
      st_u16_coh(orow + g * HB + lm, hi);          // coherent: read by other WGs
      st_u16_coh(orow + 256 + g * HB + lm, lo);    // coherent: read by other WGs
      orow[512 + g * HB + lm] = hi;  // plain: consumed only by gemm_out (post-kernel)
    }

    // manual release: drain this wave's stores to the coherent point, then
    // publish this wave's flag (relaxed atomic -> plain sc0|sc1 store, no wbl2)
    asm volatile("s_waitcnt vmcnt(0)" ::: "memory");
    if (l == 0)
      __hip_atomic_store(&flags[(g * 4 + w) * 32], (u32)(t + 1), __ATOMIC_RELAXED,
                         __HIP_MEMORY_SCOPE_AGENT);
    asm volatile("" ::: "memory");   // keep the flag store in program order
  }

#pragma unroll
  for (int r = 0; r < 4; ++r) {
    int b = 16 * w + lq * 4 + r;
    hlast[b * HID + g * HB + lm] = hown[r];
  }
}

// ---------- final GEMM: out[16384,5000] = A'[16384,768] @ B'[768,5120] + bd ----------
__global__ __launch_bounds__(256, 2) void gemm_out(
    const u16* __restrict__ A, const u16* __restrict__ BT,
    const float* __restrict__ bd, float* __restrict__ out) {
  __shared__ u16 As[128 * 32];
  __shared__ u16 Bs[128 * 32];
  const int tid = threadIdx.x;
  const int w = tid >> 6, l = tid & 63;
  const int lm = l & 15, lq = l >> 4;
  const int wm = w & 1, wn = w >> 1;
  const int m0 = blockIdx.y * 128;
  const int n0 = blockIdx.x * 128;
  const int tr = tid >> 2;        // row within 64-row group
  const int tc = (tid & 3) * 8;   // ushort col offset

  f32x4 acc[4][4] = {};

  for (int kb = 0; kb < 24; ++kb) {
    if (kb) __syncthreads();
#pragma unroll
    for (int j = 0; j < 2; ++j) {
      // LDS dest = wave-uniform base + lane*16 (layout derived to match)
      load_lds16(A  + (size_t)(m0 + j * 64 + tr) * KC + kb * 32 + tc,
                 As + j * 2048 + (tid >> 6) * 512);
      load_lds16(BT + (size_t)(n0 + j * 64 + tr) * KC + kb * 32 + tc,
                 Bs + j * 2048 + (tid >> 6) * 512);
    }
    __syncthreads();

    bf16x8 af[4], bfr[4];
#pragma unroll
    for (int mi = 0; mi < 4; ++mi)
      af[mi] = *(const bf16x8*)(As + (wm * 64 + mi * 16 + lm) * 32 + lq * 8);
#pragma unroll
    for (int ni = 0; ni < 4; ++ni)
      bfr[ni] = *(const bf16x8*)(Bs + (wn * 64 + ni * 16 + lm) * 32 + lq * 8);
#pragma unroll
    for (int mi = 0; mi < 4; ++mi)
#pragma unroll
      for (int ni = 0; ni < 4; ++ni)
        acc[mi][ni] = __builtin_amdgcn_mfma_f32_16x16x32_bf16(af[mi], bfr[ni], acc[mi][ni], 0, 0, 0);
  }

#pragma unroll
  for (int ni = 0; ni < 4; ++ni) {
    int n = n0 + wn * 64 + ni * 16 + lm;
    float bdv = (n < VOCAB) ? bd[n] : 0.f;
#pragma unroll
    for (int mi = 0; mi < 4; ++mi) {
#pragma unroll
      for (int r = 0; r < 4; ++r) {
        int m = m0 + wm * 64 + mi * 16 + lq * 4 + r;
        if (n < VOCAB) out[(size_t)m * VOCAB + n] = acc[mi][ni][r] + bdv;
      }
    }
  }
}

// ---------- launch ----------
extern "C" void kernel_launch(void* const* d_in, const int* in_sizes, int n_in,
                              void* d_out, int out_size, void* d_ws, size_t ws_size,
                              hipStream_t stream) {
  const int*   tokens = (const int*)d_in[0];
  const float* h0     = (const float*)d_in[1];
  const float* ker    = (const float*)d_in[2];
  const float* rker   = (const float*)d_in[3];
  const float* bias   = (const float*)d_in[4];
  const float* Wd     = (const float*)d_in[5];
  const float* bd     = (const float*)d_in[6];
  float* out = (float*)d_out;
  char* ws = (char*)d_ws;

  // workspace layout (bytes)
  u16* Abuf  = (u16*)(ws);              // 16384*768*2 = 25,165,824
  u16* BT    = (u16*)(ws + 25165824);   //  5120*768*2 =  7,864,320
  u16* H0S   = (u16*)(ws + 33030144);   //    64*768*2 =     98,304
  u32* flags = (u32*)(ws + 33128448);   //  64 waves * 32 u32 = 8,192

  hipMemsetAsync(flags, 0, 8192, stream);
  prep_b<<<1920, 256, 0, stream>>>(Wd, BT);
  prep_h0<<<64, 256, 0, stream>>>(h0, H0S);
  gru_rec<<<NWG, 256, 0, stream>>>(tokens, h0, ker, rker, bias, Abuf, H0S,
                                   out + (size_t)16384 * VOCAB, flags);
  gemm_out<<<dim3(40, 128), 256, 0, stream>>>(Abuf, BT, bd, out);
}